// Round 12
// baseline (124.081 us; speedup 1.0000x reference)
//
#include <hip/hip_runtime.h>

// B=4096, F0=39, D=16, L=(128,128), H1=64
// Round-12: 8 waves/SIMD via K-split waves (512-thr blocks), matching the 64-VGPR
// tier the compiler insists on (r8-r11: VGPR pinned at 64, 4 waves/SIMD -> wall
// 2.3x MFMA floor from unhidden latency; L2 traffic proven non-binding by r8~r9).
//  - Grid 1024 x 512 thr: 4 batches/block, 8 waves = col-quarter(w) x K-half(ks).
//    4 blocks/CU x 8 waves = 32 waves/CU = 8 waves/SIMD.
//  - Wave runs half the chunk list (15 L0 + 40 L1); B reads disjoint per block.
//  - K-split crosses relu: each layer ends with two-pass LDS acc-reduction
//    (ks=1 writes acc[p], barrier, ks=0 adds + relu + h/cs), ~18 KB extra LDS.
//  - mfma_f32_32x32x16_f16; A built per-chunk from one ds_read_b128 + v_pk_mul_f16
//    (r10 style, keeps pressure in the 64-VGPR tier, no spills).
//  - Layer-0 symmetric fold (30 chunks), layer-1 80; B f16 frag-order in d_ws,
//    global->VGPR, copy-free distance-2 prefetch threaded across the L0/L1 junction.
// Layouts (verified):
//  A: lane holds A[m=lane&31][k=(lane>>5)*8+t]
//  B: lane holds B[k=(lane>>5)*8+t][n=lane&31]
//  D: lane holds D[row=(r&3)+8*(r>>2)+4*(lane>>5)][col=lane&31]
// Repacked B (BYTES): ch*8192 + kh*4096 + cg*1024 + lane*16 (8 f16/lane)
//  L0 ch=0..29 (IG0/JG0): i=ig*4+kh*2+half, j=jg*8+t; folded upper-tri.
//  L1 ch=30+jg*5+ig (jg<16,ig<5): j=jg*4+kh*2+half, i=ig*8+t, zero-pad i>=39.
// Total: 110 chunks * 8192 B = 901,120 B of d_ws.

typedef _Float16 h2    __attribute__((ext_vector_type(2)));
typedef _Float16 f16x8 __attribute__((ext_vector_type(8)));
typedef __attribute__((ext_vector_type(16))) float f32x16;

#define XBB 1160   // per-batch halfs in xsH: 16 rows * 72 + 8 skew (2320 B, 16-aligned)
#define L0C 30
#define NCH 110

__device__ __constant__ int IG0[L0C] = {0,0,0,0,0, 1,1,1,1,1, 2,2,2,2, 3,3,3,3, 4,4,4, 5,5,5, 6,6, 7,7, 8, 9};
__device__ __constant__ int JG0[L0C] = {0,1,2,3,4, 0,1,2,3,4, 1,2,3,4, 1,2,3,4, 2,3,4, 2,3,4, 3,4, 3,4, 4, 4};
// compile-time tables for unrolled loops
#define IG0T(c) ((c)<5?0:(c)<10?1:(c)<14?2:(c)<18?3:(c)<21?4:(c)<24?5:(c)<26?6:(c)<28?7:(c)<29?8:9)
#define JG0T(c) ((c)<10?((c)%5):(c)<18?(((c)-10)%4+1):(c)<24?(((c)-18)%3+2):(c)<28?(((c)-24)%2+3):4)

// ---------------- weight repack (unchanged layout) ----------------
__global__ __launch_bounds__(256)
void CIN_repack(const float* __restrict__ f0, const float* __restrict__ f1,
                uint4* __restrict__ ws)
{
    const int tid  = blockIdx.x * 256 + threadIdx.x;   // 56320 total
    const int n    = tid & 127;
    const int slot = tid >> 7;                          // 0..439
    const int half = slot & 1;
    const int kh   = (slot >> 1) & 1;
    const int ch   = slot >> 2;                         // 0..109
    float v[8];
    if (ch < L0C) {
        const int ig = IG0[ch], jg = JG0[ch];
        const int i = ig * 4 + kh * 2 + half;
#pragma unroll
        for (int t = 0; t < 8; ++t) {
            const int j = jg * 8 + t;
            float val = 0.f;
            if (i < 39 && j < 39 && j >= i) {
                val = f0[(i * 39 + j) * 128 + n];
                if (j > i) val += f0[(j * 39 + i) * 128 + n];   // symmetric fold
            }
            v[t] = val;
        }
    } else {
        const int c1 = ch - L0C;
        const int jg = c1 / 5, ig = c1 - jg * 5;
        const int j = jg * 4 + kh * 2 + half;
#pragma unroll
        for (int t = 0; t < 8; ++t) {
            const int i = ig * 8 + t;
            v[t] = (i < 39) ? f1[(i * 64 + j) * 128 + n] : 0.f;
        }
    }
    union { h2 h[4]; uint4 q; } pk;
#pragma unroll
    for (int t = 0; t < 4; ++t)
        pk.h[t] = h2{(_Float16)v[2 * t], (_Float16)v[2 * t + 1]};
    const int lane = half * 32 + (n & 31);
    const int cg   = n >> 5;
    ws[ch * 512 + kh * 256 + cg * 64 + lane] = pk.q;
}

// ---------------- main: grid 1024 x 512 thr, 8 waves = colq x K-half ----------------
__global__ __launch_bounds__(512)
void CIN_main(const float* __restrict__ x,
              const char* __restrict__ wsB,
              const float* __restrict__ dw,
              const float* __restrict__ db,
              float* __restrict__ out)
{
    __shared__ __align__(16) _Float16 xsH[4 * XBB];    // [bb]: 16 rows of 72
    __shared__ __align__(4)  _Float16 hsH[4][64][18];  // [bb][j][d]
    __shared__ __align__(8)  float accst[4][64][18];   // [w][lane][16 of 18] K-half staging
    __shared__ float dws[192];
    __shared__ float red[4][4];

    const int tid  = threadIdx.x;
    const int wv   = tid >> 6;     // 0..7
    const int w    = wv & 3;       // col-quarter: n in [w*32, w*32+32)
    const int ks   = wv >> 2;      // K-half
    const int lane = tid & 63;
    const int half = lane >> 5;
    const int d    = lane & 15;
    const int bsel = (lane >> 4) & 1;
    const int col  = lane & 31;

    const char* wbase = wsB + lane * 16 + w * 1024 + 2048;  // +2048 rebase for imm13
    f16x8 Bb[2][2];                // [phase][kh]
    auto loadBg = [&](int ch, f16x8 (&B)[2]) {
        const char* p0 = wbase + (size_t)ch * 8192;
        B[0] = *(const f16x8*)(p0 - 2048);
        B[1] = *(const f16x8*)(p0 + 2048);
    };

    // wave's list: ks=0 -> L0 0..14, L1 30..69 ; ks=1 -> L0 15..29, L1 70..109
    loadBg(ks ? 15 : 0, Bb[0]);
    loadBg(ks ? 16 : 1, Bb[1]);

    // ---- stage x for 4 batches as f16 (624 float4) ----
    const float4* xg4 = (const float4*)(x + (size_t)blockIdx.x * 4 * 624);
    for (int e4 = tid; e4 < 624; e4 += 512) {
        float4 v = xg4[e4];
        int bb = e4 / 156, r = e4 - bb * 156;
        int i = r >> 2, d0 = (r & 3) * 4;
        _Float16* bp = xsH + bb * XBB + i;
        bp[(d0 + 0) * 72] = (_Float16)v.x; bp[(d0 + 1) * 72] = (_Float16)v.y;
        bp[(d0 + 2) * 72] = (_Float16)v.z; bp[(d0 + 3) * 72] = (_Float16)v.w;
    }
    if (tid < 64) { int bb = tid >> 4, dd = tid & 15; xsH[bb * XBB + dd * 72 + 39] = (_Float16)0.f; }
    if (tid < 192) dws[tid] = dw[tid];
    __syncthreads();

    const _Float16* xrow[2] = {
        xsH + (0 * 2 + bsel) * XBB + d * 72,
        xsH + (1 * 2 + bsel) * XBB + d * 72
    };

    f32x16 acc[2];
#pragma unroll
    for (int p = 0; p < 2; ++p)
#pragma unroll
        for (int r = 0; r < 16; ++r) acc[p][r] = 0.f;

    h2 xiv2[2][2];

    // helper macro body for one chunk step (A from xrow window jw, splat from xiv2)
#define CHUNK_STEP(JW, PH)                                                          \
    {                                                                               \
        _Pragma("unroll")                                                           \
        for (int p = 0; p < 2; ++p) {                                               \
            union { f16x8 v; h2 h[4]; } xj;                                         \
            xj.v = *(const f16x8*)(xrow[p] + (JW) * 8);                             \
            union { h2 h[4]; f16x8 v; } a0, a1;                                     \
            _Pragma("unroll")                                                       \
            for (int q = 0; q < 4; ++q) {                                           \
                a0.h[q] = xiv2[p][0] * xj.h[q];                                     \
                a1.h[q] = xiv2[p][1] * xj.h[q];                                     \
            }                                                                       \
            acc[p] = __builtin_amdgcn_mfma_f32_32x32x16_f16(a0.v, Bb[PH][0], acc[p], 0, 0, 0); \
            acc[p] = __builtin_amdgcn_mfma_f32_32x32x16_f16(a1.v, Bb[PH][1], acc[p], 0, 0, 0); \
        }                                                                           \
    }

    // ---------------- layer 0: this wave's 15 chunks, fully unrolled ----------------
    if (ks == 0) {
#pragma unroll
        for (int c = 0; c < 15; ++c) {
            const int ig = IG0T(c), jg = JG0T(c);
            if (c == 0 || IG0T(c) != IG0T(c - 1)) {
#pragma unroll
                for (int p = 0; p < 2; ++p)
#pragma unroll
                    for (int kh = 0; kh < 2; ++kh) {
                        _Float16 s = xrow[p][ig * 4 + kh * 2 + half];
                        xiv2[p][kh] = h2{s, s};
                    }
            }
            CHUNK_STEP(jg, c & 1)
            const int p2 = c + 2;
            loadBg(p2 < 15 ? p2 : 30 + (p2 - 15), Bb[c & 1]);
        }
    } else {
#pragma unroll
        for (int c = 0; c < 15; ++c) {
            const int cc = c + 15;
            const int ig = IG0T(cc), jg = JG0T(cc);
            if (c == 0 || IG0T(cc) != IG0T(cc - 1)) {
#pragma unroll
                for (int p = 0; p < 2; ++p)
#pragma unroll
                    for (int kh = 0; kh < 2; ++kh) {
                        _Float16 s = xrow[p][ig * 4 + kh * 2 + half];
                        xiv2[p][kh] = h2{s, s};
                    }
            }
            CHUNK_STEP(jg, c & 1)
            const int p2 = c + 2;
            loadBg(p2 < 15 ? 15 + p2 : 70 + (p2 - 15), Bb[c & 1]);
        }
    }

    // ---------------- layer-0 K-half reduction + epilogue (two-pass over p) --------
    float cs[4] = {0.f, 0.f, 0.f, 0.f};
#pragma unroll
    for (int p = 0; p < 2; ++p) {
        if (ks == 1) {
            float* dst = &accst[w][lane][0];
#pragma unroll
            for (int r = 0; r < 16; r += 2)
                *(float2*)(dst + r) = make_float2(acc[p][r], acc[p][r + 1]);
        }
        __syncthreads();
        if (ks == 0) {
            const float* src = &accst[w][lane][0];
            float z[16];
#pragma unroll
            for (int r = 0; r < 16; ++r) z[r] = acc[p][r] + src[r];
            if (w < 2) {
#pragma unroll
                for (int r = 0; r < 16; r += 2) {
                    const int row = (r & 3) + 8 * (r >> 2) + 4 * half;
                    h2 pr = h2{(_Float16)fmaxf(z[r],     0.f),
                               (_Float16)fmaxf(z[r + 1], 0.f)};
                    *(h2*)&hsH[p * 2 + (row >> 4)][w * 32 + col][row & 15] = pr;
                }
            } else {
                const float dwv = dws[(w - 2) * 32 + col];   // dw[n-64]
#pragma unroll
                for (int r = 0; r < 16; ++r) {
                    const int row = (r & 3) + 8 * (r >> 2) + 4 * half;
                    cs[p * 2 + (row >> 4)] += fmaxf(z[r], 0.f) * dwv;
                }
            }
        }
        __syncthreads();   // protects accst overwrite (p=1) and hsH visibility (end)
    }
#pragma unroll
    for (int p = 0; p < 2; ++p)
#pragma unroll
        for (int r = 0; r < 16; ++r) acc[p][r] = 0.f;

    // ---------------- layer 1: this wave's 40 chunks (4 outer x 10 unrolled) -------
    // phase: pos = 15 + o2*10 + u -> Bb[(u+1)&1]
    const int chBase = ks ? 70 : 30;
    const int jgBase = ks * 8;
#pragma unroll 1
    for (int o2 = 0; o2 < 4; ++o2) {
#pragma unroll
        for (int u = 0; u < 10; ++u) {
            const int igx = u % 5;
            if (igx == 0) {
                const int jb = (jgBase + o2 * 2 + u / 5) * 4;
#pragma unroll
                for (int p = 0; p < 2; ++p)
#pragma unroll
                    for (int kh = 0; kh < 2; ++kh) {
                        _Float16 s = hsH[p * 2 + bsel][jb + kh * 2 + half][d];
                        xiv2[p][kh] = h2{s, s};
                    }
            }
            CHUNK_STEP(igx, (u + 1) & 1)
            int idx2 = o2 * 10 + u + 2; if (idx2 > 39) idx2 = 39;
            loadBg(chBase + idx2, Bb[(u + 1) & 1]);
        }
    }

    // ---------------- layer-1 K-half reduction + epilogue (two-pass over p) --------
#pragma unroll
    for (int p = 0; p < 2; ++p) {
        if (ks == 1) {
            float* dst = &accst[w][lane][0];
#pragma unroll
            for (int r = 0; r < 16; r += 2)
                *(float2*)(dst + r) = make_float2(acc[p][r], acc[p][r + 1]);
        }
        __syncthreads();
        if (ks == 0) {
            const float* src = &accst[w][lane][0];
            const float dwv = dws[64 + w * 32 + col];
#pragma unroll
            for (int r = 0; r < 16; ++r) {
                const int row = (r & 3) + 8 * (r >> 2) + 4 * half;
                cs[p * 2 + (row >> 4)] += fmaxf(acc[p][r] + src[r], 0.f) * dwv;
            }
        }
        __syncthreads();
    }

    // ---------------- final reduction (ks=0 waves only hold cs) ----------------
    if (ks == 0) {
#pragma unroll
        for (int rr = 0; rr < 4; ++rr)
#pragma unroll
            for (int off = 32; off > 0; off >>= 1)
                cs[rr] += __shfl_xor(cs[rr], off, 64);
        if (lane == 0) {
#pragma unroll
            for (int rr = 0; rr < 4; ++rr) red[w][rr] = cs[rr];
        }
    }
    __syncthreads();
    if (tid < 4)
        out[blockIdx.x * 4 + tid] = red[0][tid] + red[1][tid] + red[2][tid] + red[3][tid] + db[0];
#undef CHUNK_STEP
}

extern "C" void kernel_launch(void* const* d_in, const int* in_sizes, int n_in,
                              void* d_out, int out_size, void* d_ws, size_t ws_size,
                              hipStream_t stream)
{
    const float* x  = (const float*)d_in[0];
    const float* f0 = (const float*)d_in[1];
    const float* f1 = (const float*)d_in[2];
    const float* dw = (const float*)d_in[3];
    const float* db = (const float*)d_in[4];
    float* out = (float*)d_out;

    CIN_repack<<<dim3(220), dim3(256), 0, stream>>>(f0, f1, (uint4*)d_ws);
    CIN_main<<<dim3(1024), dim3(512), 0, stream>>>(x, (const char*)d_ws, dw, db, out);
}